// Round 16
// baseline (242.217 us; speedup 1.0000x reference)
//
#include <hip/hip_runtime.h>

typedef unsigned short ush;
typedef unsigned int u32;
typedef __attribute__((ext_vector_type(4))) float f32x4;
typedef __attribute__((ext_vector_type(8))) short short8;
typedef __attribute__((ext_vector_type(8))) ush ushx8;
typedef __attribute__((ext_vector_type(4))) ush ushx4;

#define GAS __attribute__((address_space(1)))
#define LAS __attribute__((address_space(3)))

__device__ __forceinline__ void gl_lds16(const void* g, void* l) {
  __builtin_amdgcn_global_load_lds((const GAS void*)g, (LAS void*)l, 16, 0, 0);
}

// manual RNE f32->bf16 (proven)
__device__ __forceinline__ ush f2bf(float f) {
  union { float f; unsigned int u; } x; x.f = f;
  unsigned int r = x.u + 0x7fffu + ((x.u >> 16) & 1u);
  return (ush)(r >> 16);
}
__device__ __forceinline__ u32 fbits(float f) {
  union { float f; u32 u; } x; x.f = f; return x.u;
}

#define NEG_BIG (-1.0e4f)
// 1/sqrt(64) * log2(e): folded into Q during the QKV GEMM epilogue
#define SCL 0.18033688f

// BK=32 row swizzle: 4 chunks (16B) per row
__device__ __forceinline__ int kkey(int row) { return ((row & 3) + (row >> 2)) & 3; }

// ---- merged prep: blocks [0,4096) convert x f32->bf16; [4096,5120) transpose W
__global__ __launch_bounds__(256) void k_prep(
    const float* __restrict__ X, const float* __restrict__ W0,
    const float* __restrict__ W1, const float* __restrict__ W2,
    const float* __restrict__ W3, ush* __restrict__ Xb, ush* __restrict__ Wt) {
  __shared__ ush Ts[64][72];
  const int bx = blockIdx.x;
  if (bx < 4096) {
    int idx = bx * 256 + threadIdx.x;
    int base = idx * 8;
    f32x4 a = *(const f32x4*)(X + base);
    f32x4 b = *(const f32x4*)(X + base + 4);
    ushx8 o;
#pragma unroll
    for (int q = 0; q < 4; ++q) { o[q] = f2bf(a[q]); o[4 + q] = f2bf(b[q]); }
    *(ushx8*)(Xb + base) = o;
    return;
  }
  const int bid = bx - 4096;
  const int z = bid >> 8;
  const int k0 = (bid & 15) * 64, n0 = ((bid >> 4) & 15) * 64;
  const float* W = (z == 0) ? W0 : (z == 1) ? W1 : (z == 2) ? W2 : W3;
  ush* Ot = Wt + (size_t)z * 1048576;
  const int rr = threadIdx.x >> 4, cc = threadIdx.x & 15;
#pragma unroll
  for (int i = 0; i < 4; ++i) {
    int row = i * 16 + rr;
    f32x4 v = *(const f32x4*)(W + (size_t)(k0 + row) * 1024 + n0 + cc * 4);
#pragma unroll
    for (int q = 0; q < 4; ++q) Ts[row][cc * 4 + q] = f2bf(v[q]);
  }
  __syncthreads();
#pragma unroll
  for (int i = 0; i < 4; ++i) {
    int n = i * 16 + rr;
    ushx4 o;
#pragma unroll
    for (int q = 0; q < 4; ++q) o[q] = Ts[cc * 4 + q][n];
    *(ushx4*)(Ot + (size_t)(n0 + n) * 1024 + k0 + cc * 4) = o;
  }
}

// ---- fused QKV GEMM, 256x128 tile, BK=32, triple-buffered, counted vmcnt.
// Q output (which==0) pre-scaled by SCL. V blocks (which==2) write V^T.
__global__ __launch_bounds__(512, 2) void k_gemm_qkv(
    const ush* __restrict__ X, const ush* __restrict__ Wt,
    ush* __restrict__ QKV, ush* __restrict__ Vtg) {
  __shared__ __align__(16) ush sm[36864];   // 3 stages x (A 8192 + B 4096)
  const int tid = threadIdx.x;
  const int w = tid >> 6, l = tid & 63, lr = l & 15, lg = l >> 4;
  const int wm = w >> 2, wn = w & 3;
  const int mt = blockIdx.x, nt = blockIdx.y;
  const int which = nt >> 3, n0 = (nt & 7) * 128;
  const ush* Ag = X + (size_t)mt * 256 * 1024;
  const ush* Bg = Wt + (size_t)which * 1048576 + (size_t)n0 * 1024;
  int aoff[2], boff;
  {
#pragma unroll
    for (int it = 0; it < 2; ++it) {
      int ch = it * 512 + tid, row = ch >> 2, g = ch & 3;
      aoff[it] = row * 1024 + ((g ^ kkey(row)) << 3);
    }
    int row = tid >> 2, g = tid & 3;
    boff = row * 1024 + ((g ^ kkey(row)) << 3);
  }
  f32x4 acc[8][2] = {};

  auto issueS = [&](int kt, int st) {
    const ush* Asrc = Ag + kt * 32;
    const ush* Bsrc = Bg + kt * 32;
    ush* base = sm + st * 12288;
#pragma unroll
    for (int it = 0; it < 2; ++it)
      gl_lds16(Asrc + aoff[it], base + ((size_t)it * 512 + tid) * 8);
    gl_lds16(Bsrc + boff, base + 8192 + (size_t)tid * 8);
  };

  issueS(0, 0);
  issueS(1, 1);
  int st = 0, st2 = 2;
  for (int t = 0; t < 32; ++t) {
    if (t < 31) {
      asm volatile("s_waitcnt vmcnt(3)" ::: "memory");
    } else {
      asm volatile("s_waitcnt vmcnt(0)" ::: "memory");
    }
    __syncthreads();
    if (t + 2 < 32) issueS(t + 2, st2);
    const ush* Ab = sm + st * 12288;
    const ush* Bb = sm + st * 12288 + 8192;
    short8 fb[2];
#pragma unroll
    for (int ni = 0; ni < 2; ++ni) {
      int row = wn * 32 + ni * 16 + lr;
      fb[ni] = *(const short8*)(Bb + row * 32 + ((lg ^ kkey(row)) << 3));
    }
#pragma unroll
    for (int qm = 0; qm < 4; ++qm) {
      short8 fa[2];
#pragma unroll
      for (int m2 = 0; m2 < 2; ++m2) {
        int row = wm * 128 + (qm * 2 + m2) * 16 + lr;
        fa[m2] = *(const short8*)(Ab + row * 32 + ((lg ^ kkey(row)) << 3));
      }
      __builtin_amdgcn_s_setprio(1);
#pragma unroll
      for (int m2 = 0; m2 < 2; ++m2)
#pragma unroll
        for (int ni = 0; ni < 2; ++ni)
          acc[qm * 2 + m2][ni] = __builtin_amdgcn_mfma_f32_16x16x32_bf16(
              fa[m2], fb[ni], acc[qm * 2 + m2][ni], 0, 0, 0);
      __builtin_amdgcn_s_setprio(0);
    }
    st = (st == 2) ? 0 : st + 1;
    st2 = (st2 == 2) ? 0 : st2 + 1;
  }
  __syncthreads();
  // epilogue: bf16 C tile; Q gets pre-scaled by SCL (softmax scale folding)
  const float oscale = (which == 0) ? SCL : 1.0f;
  ush* Ct = sm;
#pragma unroll
  for (int mi = 0; mi < 8; ++mi)
#pragma unroll
    for (int ni = 0; ni < 2; ++ni)
#pragma unroll
      for (int j = 0; j < 4; ++j)
        Ct[(wm * 128 + mi * 16 + lg * 4 + j) * 128 + wn * 32 + ni * 16 + lr] =
            f2bf(acc[mi][ni][j] * oscale);
  __syncthreads();
  const int m0 = mt * 256, b = m0 >> 11, t0 = m0 & 2047, h0 = n0 >> 6;
  if (which == 2) {
    const int cc = tid & 127, rq = tid >> 7;
    const int hsel = cc >> 6, d = cc & 63;
    ush* dst = Vtg + (size_t)(b * 16 + h0 + hsel) * 131072 + (size_t)d * 2048 +
               t0 + rq * 64;
#pragma unroll
    for (int ch = 0; ch < 8; ++ch) {
      ushx8 v;
#pragma unroll
      for (int k = 0; k < 8; ++k) v[k] = Ct[(rq * 64 + ch * 8 + k) * 128 + cc];
      *(ushx8*)(dst + ch * 8) = v;
    }
  } else {
    ush* Om = QKV + (size_t)which * 8388608;
#pragma unroll
    for (int it = 0; it < 8; ++it) {
      int c = it * 512 + tid;
      int hsel = c >> 11;
      int cc = c & 2047;
      int r = cc >> 3;
      int c8 = (cc & 7) * 8;
      ushx8 v = *(const ushx8*)(Ct + r * 128 + hsel * 64 + c8);
      *(ushx8*)(Om + ((size_t)(b * 16 + h0 + hsel) * 2048 + t0 + r) * 64 + c8) = v;
    }
  }
}

// ---- causal flash attention: V staged in LDS (double-buffer), K read
// DIRECTLY from global (L2-resident; all q-blocks of a head share an XCD).
// kf registers shared by both paired q-tiles. Q pre-scaled by SCL.
__global__ __launch_bounds__(256) void k_attn(
    const ush* __restrict__ Q, const ush* __restrict__ K,
    const ush* __restrict__ Vg, ush* __restrict__ O) {
  __shared__ __align__(16) ush Vs[2][4096];   // swz [64 d][64 kv], key=((d&7)+(d>>3))&7
  __shared__ __align__(16) ush Pl[8][1024];   // per wave x {A,B}: swz [16 q][64 kv], key=q&7
  const int lid = blockIdx.x + 16 * blockIdx.y;
  const int qta = (lid >> 3) & 15;
  const int bh  = ((lid >> 7) << 3) | (lid & 7);
  const int qtb = 31 - qta;
  const size_t hb = (size_t)bh * (2048 * 64);
  const ush* Qh = Q + hb;
  const ush* Kh = K + hb;
  const ush* Vh = Vg + hb;                    // [64 d][2048 t]
  const int tid = threadIdx.x, w = tid >> 6, l = tid & 63, lr = l & 15, lg = l >> 4;
  const int q0a = qta * 64 + w * 16, q0b = qtb * 64 + w * 16;

  short8 qfa[2], qfb[2];
#pragma unroll
  for (int s = 0; s < 2; ++s) {
    qfa[s] = *(const short8*)(Qh + (size_t)(q0a + lr) * 64 + s * 32 + lg * 8);
    qfb[s] = *(const short8*)(Qh + (size_t)(q0b + lr) * 64 + s * 32 + lg * 8);
  }
  f32x4 acca[4] = {}, accb[4] = {};
  float la[4] = {0.f, 0.f, 0.f, 0.f}, lb[4] = {0.f, 0.f, 0.f, 0.f};

  int voff[2];
#pragma unroll
  for (int it = 0; it < 2; ++it) {
    int ch = it * 256 + tid;
    int r = ch >> 3, g = ch & 7;
    int keyv = ((r & 7) + (r >> 3)) & 7;
    voff[it] = r * 2048 + ((g ^ keyv) << 3);
  }
  auto issueV = [&](int c, int buf) {
#pragma unroll
    for (int it = 0; it < 2; ++it) {
      int ch = it * 256 + tid;
      gl_lds16(Vh + c * 64 + voff[it], &Vs[buf][ch * 8]);
    }
  };

  short8 kf[2][4];
  auto loadKf = [&](int c) {
#pragma unroll
    for (int s = 0; s < 2; ++s)
#pragma unroll
      for (int f = 0; f < 4; ++f)
        kf[s][f] = *(const short8*)(Kh + ((size_t)c * 64 + f * 16 + lr) * 64 +
                                    s * 32 + lg * 8);
  };

  auto ctile = [&](const ush* Vc, const short8* qf,
                   f32x4* acc, float* lrow, bool diag, ush* PlW) {
    f32x4 sf[4] = {};
    __builtin_amdgcn_s_setprio(1);
#pragma unroll
    for (int s = 0; s < 2; ++s)
#pragma unroll
      for (int f = 0; f < 4; ++f)
        sf[f] = __builtin_amdgcn_mfma_f32_16x16x32_bf16(qf[s], kf[s][f], sf[f], 0, 0, 0);
    __builtin_amdgcn_s_setprio(0);
#pragma unroll
    for (int f = 0; f < 4; ++f)
#pragma unroll
      for (int j = 0; j < 4; ++j) {
        float vv = sf[f][j];                 // Q pre-scaled: s' = s*SCL already
        if (diag && (f * 16 + lr) > (w * 16 + lg * 4 + j)) vv = NEG_BIG;
        sf[f][j] = __builtin_amdgcn_exp2f(vv);
      }
#pragma unroll
    for (int j = 0; j < 4; ++j)
      lrow[j] += (sf[0][j] + sf[1][j]) + (sf[2][j] + sf[3][j]);
#pragma unroll
    for (int f = 0; f < 4; ++f)
#pragma unroll
      for (int j = 0; j < 4; ++j) {
        int q = lg * 4 + j;
        PlW[q * 64 + ((f * 16 + lr) ^ ((q & 7) << 3))] = (ush)(fbits(sf[f][j]) >> 16);
      }
    __builtin_amdgcn_s_setprio(1);
#pragma unroll
    for (int s = 0; s < 2; ++s) {
      short8 pf = *(const short8*)(PlW + lr * 64 + (((s * 4 + lg) ^ (lr & 7)) << 3));
#pragma unroll
      for (int db = 0; db < 4; ++db) {
        int dv = db * 16 + lr;
        int keyv = ((dv & 7) + (dv >> 3)) & 7;
        short8 vf = *(const short8*)(Vc + dv * 64 + (((s * 4 + lg) ^ keyv) << 3));
        acc[db] = __builtin_amdgcn_mfma_f32_16x16x32_bf16(pf, vf, acc[db], 0, 0, 0);
      }
    }
    __builtin_amdgcn_s_setprio(0);
  };

  issueV(0, 0);
  int cur = 0;
  for (int c = 0; c <= qtb; ++c) {
    asm volatile("s_waitcnt vmcnt(0)" ::: "memory");
    __syncthreads();                  // Vs[cur] staged; fences prev compute
    if (c < qtb) issueV(c + 1, cur ^ 1);
    loadKf(c);                        // direct from L2
    const ush* Vc = Vs[cur];
    if (c <= qta) ctile(Vc, qfa, acca, la, c == qta, Pl[w]);
    ctile(Vc, qfb, accb, lb, c == qtb, Pl[4 + w]);
    cur ^= 1;
  }

#pragma unroll
  for (int msk = 1; msk <= 8; msk <<= 1)
#pragma unroll
    for (int j = 0; j < 4; ++j) {
      la[j] += __shfl_xor(la[j], msk);
      lb[j] += __shfl_xor(lb[j], msk);
    }
  float ia[4], ib[4];
#pragma unroll
  for (int j = 0; j < 4; ++j) {
    ia[j] = __builtin_amdgcn_rcpf(la[j]);
    ib[j] = __builtin_amdgcn_rcpf(lb[j]);
  }
  ush* Oh = O + hb;
#pragma unroll
  for (int db = 0; db < 4; ++db)
#pragma unroll
    for (int j = 0; j < 4; ++j) {
      Oh[(size_t)(q0a + lg * 4 + j) * 64 + db * 16 + lr] = f2bf(acca[db][j] * ia[j]);
      Oh[(size_t)(q0b + lg * 4 + j) * 64 + db * 16 + lr] = f2bf(accb[db][j] * ib[j]);
    }
}

// ---- permute, LDS-tiled: block (jh,tau,b) -> M[b][128*tau..+128][jh*128..+128]
__global__ __launch_bounds__(256) void k_gather(const ush* __restrict__ Ob, ush* __restrict__ Mb) {
  __shared__ ush Ls[2][128][68];
  const int jh = blockIdx.x, tau = blockIdx.y, b = blockIdx.z;
  const int tid = threadIdx.x;
#pragma unroll
  for (int it = 0; it < 8; ++it) {
    int c = it * 256 + tid;
    int r = c >> 3, d8 = (c & 7) * 8;
    int esel = r >> 7, jlow = r & 127;
    ushx8 v = *(const ushx8*)(Ob +
        ((size_t)(b * 16 + jh + esel * 8) * 2048 + jlow * 16 + tau) * 64 + d8);
    *(ushx8*)(&Ls[esel][jlow][d8]) = v;
  }
  __syncthreads();
  const int wv = tid >> 6, l = tid & 63;
  const int e = wv >> 1, jhalf = wv & 1, d = l;
  ush* Mrow = Mb + (size_t)b * 2097152 +
              (size_t)(128 * tau + 2 * d + e) * 1024 + jh * 128 + jhalf * 64;
#pragma unroll
  for (int ch = 0; ch < 8; ++ch) {
    ushx8 v;
#pragma unroll
    for (int k = 0; k < 8; ++k) v[k] = Ls[e][jhalf * 64 + ch * 8 + k][d];
    *(ushx8*)(Mrow + ch * 8) = v;
  }
}

// ---- output GEMM, 256x128 BK=32 triple-buffer pipeline, f32 epilogue
__global__ __launch_bounds__(512, 2) void k_gemm_out(
    const ush* __restrict__ A, const ush* __restrict__ Bt, float* __restrict__ Out) {
  __shared__ __align__(16) ush sm[36864];
  const int tid = threadIdx.x;
  const int w = tid >> 6, l = tid & 63, lr = l & 15, lg = l >> 4;
  const int wm = w >> 2, wn = w & 3;
  const int mt = blockIdx.x, nt = blockIdx.y;
  const int n0 = nt * 128;
  const ush* Ag = A + (size_t)mt * 256 * 1024;
  const ush* Bg = Bt + (size_t)n0 * 1024;
  int aoff[2], boff;
  {
#pragma unroll
    for (int it = 0; it < 2; ++it) {
      int ch = it * 512 + tid, row = ch >> 2, g = ch & 3;
      aoff[it] = row * 1024 + ((g ^ kkey(row)) << 3);
    }
    int row = tid >> 2, g = tid & 3;
    boff = row * 1024 + ((g ^ kkey(row)) << 3);
  }
  f32x4 acc[8][2] = {};

  auto issueS = [&](int kt, int st) {
    const ush* Asrc = Ag + kt * 32;
    const ush* Bsrc = Bg + kt * 32;
    ush* base = sm + st * 12288;
#pragma unroll
    for (int it = 0; it < 2; ++it)
      gl_lds16(Asrc + aoff[it], base + ((size_t)it * 512 + tid) * 8);
    gl_lds16(Bsrc + boff, base + 8192 + (size_t)tid * 8);
  };

  issueS(0, 0);
  issueS(1, 1);
  int st = 0, st2 = 2;
  for (int t = 0; t < 32; ++t) {
    if (t < 31) {
      asm volatile("s_waitcnt vmcnt(3)" ::: "memory");
    } else {
      asm volatile("s_waitcnt vmcnt(0)" ::: "memory");
    }
    __syncthreads();
    if (t + 2 < 32) issueS(t + 2, st2);
    const ush* Ab = sm + st * 12288;
    const ush* Bb = sm + st * 12288 + 8192;
    short8 fb[2];
#pragma unroll
    for (int ni = 0; ni < 2; ++ni) {
      int row = wn * 32 + ni * 16 + lr;
      fb[ni] = *(const short8*)(Bb + row * 32 + ((lg ^ kkey(row)) << 3));
    }
#pragma unroll
    for (int qm = 0; qm < 4; ++qm) {
      short8 fa[2];
#pragma unroll
      for (int m2 = 0; m2 < 2; ++m2) {
        int row = wm * 128 + (qm * 2 + m2) * 16 + lr;
        fa[m2] = *(const short8*)(Ab + row * 32 + ((lg ^ kkey(row)) << 3));
      }
      __builtin_amdgcn_s_setprio(1);
#pragma unroll
      for (int m2 = 0; m2 < 2; ++m2)
#pragma unroll
        for (int ni = 0; ni < 2; ++ni)
          acc[qm * 2 + m2][ni] = __builtin_amdgcn_mfma_f32_16x16x32_bf16(
              fa[m2], fb[ni], acc[qm * 2 + m2][ni], 0, 0, 0);
      __builtin_amdgcn_s_setprio(0);
    }
    st = (st == 2) ? 0 : st + 1;
    st2 = (st2 == 2) ? 0 : st2 + 1;
  }
  const int m0 = mt * 256;
#pragma unroll
  for (int mi = 0; mi < 8; ++mi)
#pragma unroll
    for (int ni = 0; ni < 2; ++ni)
#pragma unroll
      for (int j = 0; j < 4; ++j)
        Out[(size_t)(m0 + wm * 128 + mi * 16 + lg * 4 + j) * 1024 +
            n0 + wn * 32 + ni * 16 + lr] = acc[mi][ni][j];
}

extern "C" void kernel_launch(void* const* d_in, const int* in_sizes, int n_in,
                              void* d_out, int out_size, void* d_ws, size_t ws_size,
                              hipStream_t stream) {
  const float* x  = (const float*)d_in[0];
  const float* wq = (const float*)d_in[1];
  const float* wk = (const float*)d_in[2];
  const float* wv = (const float*)d_in[3];
  const float* wp = (const float*)d_in[4];
  float* out = (float*)d_out;   // reference output dtype is float32
  char* ws = (char*)d_ws;
  ush* xb  = (ush*)ws;                 // [0,16MB): x bf16; dead after qkv GEMM
  ush* wt  = (ush*)(ws + 16777216);    // [16,24MB): Wq^T,Wk^T,Wv^T,Wp^T bf16
  ush* qkv = (ush*)(ws + 25165824);    // [24,72MB): Q(pre-scaled),K
  ush* vtg = (ush*)(ws + 75497472);    // [72,88MB): V^T [bh][64][2048]
  ush* ob  = qkv;                      // attn out aliases Q (own-rows r->w)
  ush* mb  = xb;                       // permuted M reuses xb after attn

  k_prep<<<dim3(5120), 256, 0, stream>>>(x, wq, wk, wv, wp, xb, wt);
  k_gemm_qkv<<<dim3(32, 24), 512, 0, stream>>>(xb, wt, qkv, vtg);
  k_attn<<<dim3(16, 64), 256, 0, stream>>>(qkv, qkv + 8388608, vtg, ob);
  k_gather<<<dim3(8, 16, 4), 256, 0, stream>>>(ob, mb);
  k_gemm_out<<<dim3(32, 8), 512, 0, stream>>>(mb, wt + 3145728, out);
}

// Round 17
// 192.794 us; speedup vs baseline: 1.2563x; 1.2563x over previous
//
#include <hip/hip_runtime.h>

typedef unsigned short ush;
typedef unsigned int u32;
typedef __attribute__((ext_vector_type(4))) float f32x4;
typedef __attribute__((ext_vector_type(8))) short short8;
typedef __attribute__((ext_vector_type(8))) ush ushx8;
typedef __attribute__((ext_vector_type(4))) ush ushx4;

#define GAS __attribute__((address_space(1)))
#define LAS __attribute__((address_space(3)))

__device__ __forceinline__ void gl_lds16(const void* g, void* l) {
  __builtin_amdgcn_global_load_lds((const GAS void*)g, (LAS void*)l, 16, 0, 0);
}

// manual RNE f32->bf16 (proven)
__device__ __forceinline__ ush f2bf(float f) {
  union { float f; unsigned int u; } x; x.f = f;
  unsigned int r = x.u + 0x7fffu + ((x.u >> 16) & 1u);
  return (ush)(r >> 16);
}
__device__ __forceinline__ u32 fbits(float f) {
  union { float f; u32 u; } x; x.f = f; return x.u;
}

#define NEG_BIG (-1.0e4f)
// 1/sqrt(64) * log2(e): folded into Q during the QKV GEMM epilogue
#define SCL 0.18033688f

// BK=32 row swizzle: 4 chunks (16B) per row
__device__ __forceinline__ int kkey(int row) { return ((row & 3) + (row >> 2)) & 3; }

// ---- merged prep: blocks [0,4096) convert x f32->bf16; [4096,5120) transpose W
__global__ __launch_bounds__(256) void k_prep(
    const float* __restrict__ X, const float* __restrict__ W0,
    const float* __restrict__ W1, const float* __restrict__ W2,
    const float* __restrict__ W3, ush* __restrict__ Xb, ush* __restrict__ Wt) {
  __shared__ ush Ts[64][72];
  const int bx = blockIdx.x;
  if (bx < 4096) {
    int idx = bx * 256 + threadIdx.x;
    int base = idx * 8;
    f32x4 a = *(const f32x4*)(X + base);
    f32x4 b = *(const f32x4*)(X + base + 4);
    ushx8 o;
#pragma unroll
    for (int q = 0; q < 4; ++q) { o[q] = f2bf(a[q]); o[4 + q] = f2bf(b[q]); }
    *(ushx8*)(Xb + base) = o;
    return;
  }
  const int bid = bx - 4096;
  const int z = bid >> 8;
  const int k0 = (bid & 15) * 64, n0 = ((bid >> 4) & 15) * 64;
  const float* W = (z == 0) ? W0 : (z == 1) ? W1 : (z == 2) ? W2 : W3;
  ush* Ot = Wt + (size_t)z * 1048576;
  const int rr = threadIdx.x >> 4, cc = threadIdx.x & 15;
#pragma unroll
  for (int i = 0; i < 4; ++i) {
    int row = i * 16 + rr;
    f32x4 v = *(const f32x4*)(W + (size_t)(k0 + row) * 1024 + n0 + cc * 4);
#pragma unroll
    for (int q = 0; q < 4; ++q) Ts[row][cc * 4 + q] = f2bf(v[q]);
  }
  __syncthreads();
#pragma unroll
  for (int i = 0; i < 4; ++i) {
    int n = i * 16 + rr;
    ushx4 o;
#pragma unroll
    for (int q = 0; q < 4; ++q) o[q] = Ts[cc * 4 + q][n];
    *(ushx4*)(Ot + (size_t)(n0 + n) * 1024 + k0 + cc * 4) = o;
  }
}

// ---- fused QKV GEMM, 256x128 tile, BK=32, triple-buffered, counted vmcnt.
// Q output (which==0) pre-scaled by SCL. V blocks (which==2) write V^T.
__global__ __launch_bounds__(512, 2) void k_gemm_qkv(
    const ush* __restrict__ X, const ush* __restrict__ Wt,
    ush* __restrict__ QKV, ush* __restrict__ Vtg) {
  __shared__ __align__(16) ush sm[36864];   // 3 stages x (A 8192 + B 4096)
  const int tid = threadIdx.x;
  const int w = tid >> 6, l = tid & 63, lr = l & 15, lg = l >> 4;
  const int wm = w >> 2, wn = w & 3;
  const int mt = blockIdx.x, nt = blockIdx.y;
  const int which = nt >> 3, n0 = (nt & 7) * 128;
  const ush* Ag = X + (size_t)mt * 256 * 1024;
  const ush* Bg = Wt + (size_t)which * 1048576 + (size_t)n0 * 1024;
  int aoff[2], boff;
  {
#pragma unroll
    for (int it = 0; it < 2; ++it) {
      int ch = it * 512 + tid, row = ch >> 2, g = ch & 3;
      aoff[it] = row * 1024 + ((g ^ kkey(row)) << 3);
    }
    int row = tid >> 2, g = tid & 3;
    boff = row * 1024 + ((g ^ kkey(row)) << 3);
  }
  f32x4 acc[8][2] = {};

  auto issueS = [&](int kt, int st) {
    const ush* Asrc = Ag + kt * 32;
    const ush* Bsrc = Bg + kt * 32;
    ush* base = sm + st * 12288;
#pragma unroll
    for (int it = 0; it < 2; ++it)
      gl_lds16(Asrc + aoff[it], base + ((size_t)it * 512 + tid) * 8);
    gl_lds16(Bsrc + boff, base + 8192 + (size_t)tid * 8);
  };

  issueS(0, 0);
  issueS(1, 1);
  int st = 0, st2 = 2;
  for (int t = 0; t < 32; ++t) {
    if (t < 31) {
      asm volatile("s_waitcnt vmcnt(3)" ::: "memory");
    } else {
      asm volatile("s_waitcnt vmcnt(0)" ::: "memory");
    }
    __syncthreads();
    if (t + 2 < 32) issueS(t + 2, st2);
    const ush* Ab = sm + st * 12288;
    const ush* Bb = sm + st * 12288 + 8192;
    short8 fb[2];
#pragma unroll
    for (int ni = 0; ni < 2; ++ni) {
      int row = wn * 32 + ni * 16 + lr;
      fb[ni] = *(const short8*)(Bb + row * 32 + ((lg ^ kkey(row)) << 3));
    }
#pragma unroll
    for (int qm = 0; qm < 4; ++qm) {
      short8 fa[2];
#pragma unroll
      for (int m2 = 0; m2 < 2; ++m2) {
        int row = wm * 128 + (qm * 2 + m2) * 16 + lr;
        fa[m2] = *(const short8*)(Ab + row * 32 + ((lg ^ kkey(row)) << 3));
      }
      __builtin_amdgcn_s_setprio(1);
#pragma unroll
      for (int m2 = 0; m2 < 2; ++m2)
#pragma unroll
        for (int ni = 0; ni < 2; ++ni)
          acc[qm * 2 + m2][ni] = __builtin_amdgcn_mfma_f32_16x16x32_bf16(
              fa[m2], fb[ni], acc[qm * 2 + m2][ni], 0, 0, 0);
      __builtin_amdgcn_s_setprio(0);
    }
    st = (st == 2) ? 0 : st + 1;
    st2 = (st2 == 2) ? 0 : st2 + 1;
  }
  __syncthreads();
  // epilogue: bf16 C tile; Q gets pre-scaled by SCL (softmax scale folding)
  const float oscale = (which == 0) ? SCL : 1.0f;
  ush* Ct = sm;
#pragma unroll
  for (int mi = 0; mi < 8; ++mi)
#pragma unroll
    for (int ni = 0; ni < 2; ++ni)
#pragma unroll
      for (int j = 0; j < 4; ++j)
        Ct[(wm * 128 + mi * 16 + lg * 4 + j) * 128 + wn * 32 + ni * 16 + lr] =
            f2bf(acc[mi][ni][j] * oscale);
  __syncthreads();
  const int m0 = mt * 256, b = m0 >> 11, t0 = m0 & 2047, h0 = n0 >> 6;
  if (which == 2) {
    const int cc = tid & 127, rq = tid >> 7;
    const int hsel = cc >> 6, d = cc & 63;
    ush* dst = Vtg + (size_t)(b * 16 + h0 + hsel) * 131072 + (size_t)d * 2048 +
               t0 + rq * 64;
#pragma unroll
    for (int ch = 0; ch < 8; ++ch) {
      ushx8 v;
#pragma unroll
      for (int k = 0; k < 8; ++k) v[k] = Ct[(rq * 64 + ch * 8 + k) * 128 + cc];
      *(ushx8*)(dst + ch * 8) = v;
    }
  } else {
    ush* Om = QKV + (size_t)which * 8388608;
#pragma unroll
    for (int it = 0; it < 8; ++it) {
      int c = it * 512 + tid;
      int hsel = c >> 11;
      int cc = c & 2047;
      int r = cc >> 3;
      int c8 = (cc & 7) * 8;
      ushx8 v = *(const ushx8*)(Ct + r * 128 + hsel * 64 + c8);
      *(ushx8*)(Om + ((size_t)(b * 16 + h0 + hsel) * 2048 + t0 + r) * 64 + c8) = v;
    }
  }
}

// ---- causal flash attention (round-15 proven staging structure):
// K and V^T staged via global_load_lds, double-buffered, single barrier/step.
// Q pre-scaled by SCL; setprio around MFMA clusters.
__global__ __launch_bounds__(256) void k_attn(
    const ush* __restrict__ Q, const ush* __restrict__ K,
    const ush* __restrict__ Vg, ush* __restrict__ O) {
  __shared__ __align__(16) ush Ks[2][4096];   // swz [64 kv][64 d], key=kv&7
  __shared__ __align__(16) ush Vs[2][4096];   // swz [64 d][64 kv], key=((d&7)+(d>>3))&7
  __shared__ __align__(16) ush Pl[8][1024];   // per wave x {A,B}: swz [16 q][64 kv], key=q&7
  const int lid = blockIdx.x + 16 * blockIdx.y;
  const int qta = (lid >> 3) & 15;
  const int bh  = ((lid >> 7) << 3) | (lid & 7);
  const int qtb = 31 - qta;
  const size_t hb = (size_t)bh * (2048 * 64);
  const ush* Qh = Q + hb;
  const ush* Kh = K + hb;
  const ush* Vh = Vg + hb;                    // [64 d][2048 t]
  const int tid = threadIdx.x, w = tid >> 6, l = tid & 63, lr = l & 15, lg = l >> 4;
  const int q0a = qta * 64 + w * 16, q0b = qtb * 64 + w * 16;

  short8 qfa[2], qfb[2];
#pragma unroll
  for (int s = 0; s < 2; ++s) {
    qfa[s] = *(const short8*)(Qh + (size_t)(q0a + lr) * 64 + s * 32 + lg * 8);
    qfb[s] = *(const short8*)(Qh + (size_t)(q0b + lr) * 64 + s * 32 + lg * 8);
  }
  f32x4 acca[4] = {}, accb[4] = {};
  float la[4] = {0.f, 0.f, 0.f, 0.f}, lb[4] = {0.f, 0.f, 0.f, 0.f};

  int koff[2], voff[2];
#pragma unroll
  for (int it = 0; it < 2; ++it) {
    int ch = it * 256 + tid;
    int r = ch >> 3, g = ch & 7;
    koff[it] = r * 64 + ((g ^ (r & 7)) << 3);
    int keyv = ((r & 7) + (r >> 3)) & 7;
    voff[it] = r * 2048 + ((g ^ keyv) << 3);
  }
  auto issueStage = [&](int c, int buf) {
#pragma unroll
    for (int it = 0; it < 2; ++it) {
      int ch = it * 256 + tid;
      gl_lds16(Kh + (size_t)c * 4096 + koff[it], &Ks[buf][ch * 8]);
      gl_lds16(Vh + c * 64 + voff[it], &Vs[buf][ch * 8]);
    }
  };

  auto ctile = [&](const ush* Kc, const ush* Vc, const short8* qf,
                   f32x4* acc, float* lrow, bool diag, ush* PlW) {
    f32x4 sf[4] = {};
    __builtin_amdgcn_s_setprio(1);
#pragma unroll
    for (int s = 0; s < 2; ++s)
#pragma unroll
      for (int f = 0; f < 4; ++f) {
        int kv = f * 16 + lr;
        short8 kf = *(const short8*)(Kc + kv * 64 + (((s * 4 + lg) ^ (kv & 7)) << 3));
        sf[f] = __builtin_amdgcn_mfma_f32_16x16x32_bf16(qf[s], kf, sf[f], 0, 0, 0);
      }
    __builtin_amdgcn_s_setprio(0);
#pragma unroll
    for (int f = 0; f < 4; ++f)
#pragma unroll
      for (int j = 0; j < 4; ++j) {
        float vv = sf[f][j];                 // Q pre-scaled by SCL
        if (diag && (f * 16 + lr) > (w * 16 + lg * 4 + j)) vv = NEG_BIG;
        sf[f][j] = __builtin_amdgcn_exp2f(vv);
      }
#pragma unroll
    for (int j = 0; j < 4; ++j)
      lrow[j] += (sf[0][j] + sf[1][j]) + (sf[2][j] + sf[3][j]);
#pragma unroll
    for (int f = 0; f < 4; ++f)
#pragma unroll
      for (int j = 0; j < 4; ++j) {
        int q = lg * 4 + j;
        PlW[q * 64 + ((f * 16 + lr) ^ ((q & 7) << 3))] = (ush)(fbits(sf[f][j]) >> 16);
      }
    __builtin_amdgcn_s_setprio(1);
#pragma unroll
    for (int s = 0; s < 2; ++s) {
      short8 pf = *(const short8*)(PlW + lr * 64 + (((s * 4 + lg) ^ (lr & 7)) << 3));
#pragma unroll
      for (int db = 0; db < 4; ++db) {
        int dv = db * 16 + lr;
        int keyv = ((dv & 7) + (dv >> 3)) & 7;
        short8 vf = *(const short8*)(Vc + dv * 64 + (((s * 4 + lg) ^ keyv) << 3));
        acc[db] = __builtin_amdgcn_mfma_f32_16x16x32_bf16(pf, vf, acc[db], 0, 0, 0);
      }
    }
    __builtin_amdgcn_s_setprio(0);
  };

  issueStage(0, 0);
  int cur = 0;
  for (int c = 0; c <= qtb; ++c) {
    asm volatile("s_waitcnt vmcnt(0)" ::: "memory");
    __syncthreads();                  // buf[cur] staged; also fences prev compute
    if (c < qtb) issueStage(c + 1, cur ^ 1);
    const ush* Kc = Ks[cur];
    const ush* Vc = Vs[cur];
    if (c <= qta) ctile(Kc, Vc, qfa, acca, la, c == qta, Pl[w]);
    ctile(Kc, Vc, qfb, accb, lb, c == qtb, Pl[4 + w]);
    cur ^= 1;
  }

#pragma unroll
  for (int msk = 1; msk <= 8; msk <<= 1)
#pragma unroll
    for (int j = 0; j < 4; ++j) {
      la[j] += __shfl_xor(la[j], msk);
      lb[j] += __shfl_xor(lb[j], msk);
    }
  float ia[4], ib[4];
#pragma unroll
  for (int j = 0; j < 4; ++j) {
    ia[j] = __builtin_amdgcn_rcpf(la[j]);
    ib[j] = __builtin_amdgcn_rcpf(lb[j]);
  }
  ush* Oh = O + hb;
#pragma unroll
  for (int db = 0; db < 4; ++db)
#pragma unroll
    for (int j = 0; j < 4; ++j) {
      Oh[(size_t)(q0a + lg * 4 + j) * 64 + db * 16 + lr] = f2bf(acca[db][j] * ia[j]);
      Oh[(size_t)(q0b + lg * 4 + j) * 64 + db * 16 + lr] = f2bf(accb[db][j] * ib[j]);
    }
}

// ---- permute, LDS-tiled: block (jh,tau,b) -> M[b][128*tau..+128][jh*128..+128]
__global__ __launch_bounds__(256) void k_gather(const ush* __restrict__ Ob, ush* __restrict__ Mb) {
  __shared__ ush Ls[2][128][68];
  const int jh = blockIdx.x, tau = blockIdx.y, b = blockIdx.z;
  const int tid = threadIdx.x;
#pragma unroll
  for (int it = 0; it < 8; ++it) {
    int c = it * 256 + tid;
    int r = c >> 3, d8 = (c & 7) * 8;
    int esel = r >> 7, jlow = r & 127;
    ushx8 v = *(const ushx8*)(Ob +
        ((size_t)(b * 16 + jh + esel * 8) * 2048 + jlow * 16 + tau) * 64 + d8);
    *(ushx8*)(&Ls[esel][jlow][d8]) = v;
  }
  __syncthreads();
  const int wv = tid >> 6, l = tid & 63;
  const int e = wv >> 1, jhalf = wv & 1, d = l;
  ush* Mrow = Mb + (size_t)b * 2097152 +
              (size_t)(128 * tau + 2 * d + e) * 1024 + jh * 128 + jhalf * 64;
#pragma unroll
  for (int ch = 0; ch < 8; ++ch) {
    ushx8 v;
#pragma unroll
    for (int k = 0; k < 8; ++k) v[k] = Ls[e][jhalf * 64 + ch * 8 + k][d];
    *(ushx8*)(Mrow + ch * 8) = v;
  }
}

// ---- output GEMM, 256x128 BK=32 triple-buffer pipeline, f32 epilogue
__global__ __launch_bounds__(512, 2) void k_gemm_out(
    const ush* __restrict__ A, const ush* __restrict__ Bt, float* __restrict__ Out) {
  __shared__ __align__(16) ush sm[36864];
  const int tid = threadIdx.x;
  const int w = tid >> 6, l = tid & 63, lr = l & 15, lg = l >> 4;
  const int wm = w >> 2, wn = w & 3;
  const int mt = blockIdx.x, nt = blockIdx.y;
  const int n0 = nt * 128;
  const ush* Ag = A + (size_t)mt * 256 * 1024;
  const ush* Bg = Bt + (size_t)n0 * 1024;
  int aoff[2], boff;
  {
#pragma unroll
    for (int it = 0; it < 2; ++it) {
      int ch = it * 512 + tid, row = ch >> 2, g = ch & 3;
      aoff[it] = row * 1024 + ((g ^ kkey(row)) << 3);
    }
    int row = tid >> 2, g = tid & 3;
    boff = row * 1024 + ((g ^ kkey(row)) << 3);
  }
  f32x4 acc[8][2] = {};

  auto issueS = [&](int kt, int st) {
    const ush* Asrc = Ag + kt * 32;
    const ush* Bsrc = Bg + kt * 32;
    ush* base = sm + st * 12288;
#pragma unroll
    for (int it = 0; it < 2; ++it)
      gl_lds16(Asrc + aoff[it], base + ((size_t)it * 512 + tid) * 8);
    gl_lds16(Bsrc + boff, base + 8192 + (size_t)tid * 8);
  };

  issueS(0, 0);
  issueS(1, 1);
  int st = 0, st2 = 2;
  for (int t = 0; t < 32; ++t) {
    if (t < 31) {
      asm volatile("s_waitcnt vmcnt(3)" ::: "memory");
    } else {
      asm volatile("s_waitcnt vmcnt(0)" ::: "memory");
    }
    __syncthreads();
    if (t + 2 < 32) issueS(t + 2, st2);
    const ush* Ab = sm + st * 12288;
    const ush* Bb = sm + st * 12288 + 8192;
    short8 fb[2];
#pragma unroll
    for (int ni = 0; ni < 2; ++ni) {
      int row = wn * 32 + ni * 16 + lr;
      fb[ni] = *(const short8*)(Bb + row * 32 + ((lg ^ kkey(row)) << 3));
    }
#pragma unroll
    for (int qm = 0; qm < 4; ++qm) {
      short8 fa[2];
#pragma unroll
      for (int m2 = 0; m2 < 2; ++m2) {
        int row = wm * 128 + (qm * 2 + m2) * 16 + lr;
        fa[m2] = *(const short8*)(Ab + row * 32 + ((lg ^ kkey(row)) << 3));
      }
      __builtin_amdgcn_s_setprio(1);
#pragma unroll
      for (int m2 = 0; m2 < 2; ++m2)
#pragma unroll
        for (int ni = 0; ni < 2; ++ni)
          acc[qm * 2 + m2][ni] = __builtin_amdgcn_mfma_f32_16x16x32_bf16(
              fa[m2], fb[ni], acc[qm * 2 + m2][ni], 0, 0, 0);
      __builtin_amdgcn_s_setprio(0);
    }
    st = (st == 2) ? 0 : st + 1;
    st2 = (st2 == 2) ? 0 : st2 + 1;
  }
  const int m0 = mt * 256;
#pragma unroll
  for (int mi = 0; mi < 8; ++mi)
#pragma unroll
    for (int ni = 0; ni < 2; ++ni)
#pragma unroll
      for (int j = 0; j < 4; ++j)
        Out[(size_t)(m0 + wm * 128 + mi * 16 + lg * 4 + j) * 1024 +
            n0 + wn * 32 + ni * 16 + lr] = acc[mi][ni][j];
}

extern "C" void kernel_launch(void* const* d_in, const int* in_sizes, int n_in,
                              void* d_out, int out_size, void* d_ws, size_t ws_size,
                              hipStream_t stream) {
  const float* x  = (const float*)d_in[0];
  const float* wq = (const float*)d_in[1];
  const float* wk = (const float*)d_in[2];
  const float* wv = (const float*)d_in[3];
  const float* wp = (const float*)d_in[4];
  float* out = (float*)d_out;   // reference output dtype is float32
  char* ws = (char*)d_ws;
  ush* xb  = (ush*)ws;                 // [0,16MB): x bf16; dead after qkv GEMM
  ush* wt  = (ush*)(ws + 16777216);    // [16,24MB): Wq^T,Wk^T,Wv^T,Wp^T bf16
  ush* qkv = (ush*)(ws + 25165824);    // [24,72MB): Q(pre-scaled),K
  ush* vtg = (ush*)(ws + 75497472);    // [72,88MB): V^T [bh][64][2048]
  ush* ob  = qkv;                      // attn out aliases Q (own-rows r->w)
  ush* mb  = xb;                       // permuted M reuses xb after attn

  k_prep<<<dim3(5120), 256, 0, stream>>>(x, wq, wk, wv, wp, xb, wt);
  k_gemm_qkv<<<dim3(32, 24), 512, 0, stream>>>(xb, wt, qkv, vtg);
  k_attn<<<dim3(16, 64), 256, 0, stream>>>(qkv, qkv + 8388608, vtg, ob);
  k_gather<<<dim3(8, 16, 4), 256, 0, stream>>>(ob, mb);
  k_gemm_out<<<dim3(32, 8), 512, 0, stream>>>(mb, wt + 3145728, out);
}

// Round 18
// 189.702 us; speedup vs baseline: 1.2768x; 1.0163x over previous
//
#include <hip/hip_runtime.h>

typedef unsigned short ush;
typedef unsigned int u32;
typedef __attribute__((ext_vector_type(4))) float f32x4;
typedef __attribute__((ext_vector_type(2))) u32 u32x2;
typedef __attribute__((ext_vector_type(8))) short short8;
typedef __attribute__((ext_vector_type(8))) ush ushx8;
typedef __attribute__((ext_vector_type(4))) ush ushx4;

#define GAS __attribute__((address_space(1)))
#define LAS __attribute__((address_space(3)))

__device__ __forceinline__ void gl_lds16(const void* g, void* l) {
  __builtin_amdgcn_global_load_lds((const GAS void*)g, (LAS void*)l, 16, 0, 0);
}

// manual RNE f32->bf16 (proven)
__device__ __forceinline__ ush f2bf(float f) {
  union { float f; unsigned int u; } x; x.f = f;
  unsigned int r = x.u + 0x7fffu + ((x.u >> 16) & 1u);
  return (ush)(r >> 16);
}
__device__ __forceinline__ u32 fbits(float f) {
  union { float f; u32 u; } x; x.f = f; return x.u;
}

#define NEG_BIG (-1.0e4f)
// 1/sqrt(64) * log2(e): folded into Q during the QKV GEMM epilogue
#define SCL 0.18033688f

// BK=32 row swizzle: 4 chunks (16B) per row
__device__ __forceinline__ int kkey(int row) { return ((row & 3) + (row >> 2)) & 3; }

// ---- merged prep: blocks [0,4096) convert x f32->bf16; [4096,5120) transpose W
__global__ __launch_bounds__(256) void k_prep(
    const float* __restrict__ X, const float* __restrict__ W0,
    const float* __restrict__ W1, const float* __restrict__ W2,
    const float* __restrict__ W3, ush* __restrict__ Xb, ush* __restrict__ Wt) {
  __shared__ ush Ts[64][72];
  const int bx = blockIdx.x;
  if (bx < 4096) {
    int idx = bx * 256 + threadIdx.x;
    int base = idx * 8;
    f32x4 a = *(const f32x4*)(X + base);
    f32x4 b = *(const f32x4*)(X + base + 4);
    ushx8 o;
#pragma unroll
    for (int q = 0; q < 4; ++q) { o[q] = f2bf(a[q]); o[4 + q] = f2bf(b[q]); }
    *(ushx8*)(Xb + base) = o;
    return;
  }
  const int bid = bx - 4096;
  const int z = bid >> 8;
  const int k0 = (bid & 15) * 64, n0 = ((bid >> 4) & 15) * 64;
  const float* W = (z == 0) ? W0 : (z == 1) ? W1 : (z == 2) ? W2 : W3;
  ush* Ot = Wt + (size_t)z * 1048576;
  const int rr = threadIdx.x >> 4, cc = threadIdx.x & 15;
#pragma unroll
  for (int i = 0; i < 4; ++i) {
    int row = i * 16 + rr;
    f32x4 v = *(const f32x4*)(W + (size_t)(k0 + row) * 1024 + n0 + cc * 4);
#pragma unroll
    for (int q = 0; q < 4; ++q) Ts[row][cc * 4 + q] = f2bf(v[q]);
  }
  __syncthreads();
#pragma unroll
  for (int i = 0; i < 4; ++i) {
    int n = i * 16 + rr;
    ushx4 o;
#pragma unroll
    for (int q = 0; q < 4; ++q) o[q] = Ts[cc * 4 + q][n];
    *(ushx4*)(Ot + (size_t)(n0 + n) * 1024 + k0 + cc * 4) = o;
  }
}

// ---- fused QKV GEMM, 256x128 tile, BK=32, triple-buffered, counted vmcnt.
// Q output (which==0) pre-scaled by SCL. V blocks (which==2) write V^T.
__global__ __launch_bounds__(512, 2) void k_gemm_qkv(
    const ush* __restrict__ X, const ush* __restrict__ Wt,
    ush* __restrict__ QKV, ush* __restrict__ Vtg) {
  __shared__ __align__(16) ush sm[36864];   // 3 stages x (A 8192 + B 4096)
  const int tid = threadIdx.x;
  const int w = tid >> 6, l = tid & 63, lr = l & 15, lg = l >> 4;
  const int wm = w >> 2, wn = w & 3;
  const int mt = blockIdx.x, nt = blockIdx.y;
  const int which = nt >> 3, n0 = (nt & 7) * 128;
  const ush* Ag = X + (size_t)mt * 256 * 1024;
  const ush* Bg = Wt + (size_t)which * 1048576 + (size_t)n0 * 1024;
  int aoff[2], boff;
  {
#pragma unroll
    for (int it = 0; it < 2; ++it) {
      int ch = it * 512 + tid, row = ch >> 2, g = ch & 3;
      aoff[it] = row * 1024 + ((g ^ kkey(row)) << 3);
    }
    int row = tid >> 2, g = tid & 3;
    boff = row * 1024 + ((g ^ kkey(row)) << 3);
  }
  f32x4 acc[8][2] = {};

  auto issueS = [&](int kt, int st) {
    const ush* Asrc = Ag + kt * 32;
    const ush* Bsrc = Bg + kt * 32;
    ush* base = sm + st * 12288;
#pragma unroll
    for (int it = 0; it < 2; ++it)
      gl_lds16(Asrc + aoff[it], base + ((size_t)it * 512 + tid) * 8);
    gl_lds16(Bsrc + boff, base + 8192 + (size_t)tid * 8);
  };

  issueS(0, 0);
  issueS(1, 1);
  int st = 0, st2 = 2;
  for (int t = 0; t < 32; ++t) {
    if (t < 31) {
      asm volatile("s_waitcnt vmcnt(3)" ::: "memory");
    } else {
      asm volatile("s_waitcnt vmcnt(0)" ::: "memory");
    }
    __syncthreads();
    if (t + 2 < 32) issueS(t + 2, st2);
    const ush* Ab = sm + st * 12288;
    const ush* Bb = sm + st * 12288 + 8192;
    short8 fb[2];
#pragma unroll
    for (int ni = 0; ni < 2; ++ni) {
      int row = wn * 32 + ni * 16 + lr;
      fb[ni] = *(const short8*)(Bb + row * 32 + ((lg ^ kkey(row)) << 3));
    }
#pragma unroll
    for (int qm = 0; qm < 4; ++qm) {
      short8 fa[2];
#pragma unroll
      for (int m2 = 0; m2 < 2; ++m2) {
        int row = wm * 128 + (qm * 2 + m2) * 16 + lr;
        fa[m2] = *(const short8*)(Ab + row * 32 + ((lg ^ kkey(row)) << 3));
      }
      __builtin_amdgcn_s_setprio(1);
#pragma unroll
      for (int m2 = 0; m2 < 2; ++m2)
#pragma unroll
        for (int ni = 0; ni < 2; ++ni)
          acc[qm * 2 + m2][ni] = __builtin_amdgcn_mfma_f32_16x16x32_bf16(
              fa[m2], fb[ni], acc[qm * 2 + m2][ni], 0, 0, 0);
      __builtin_amdgcn_s_setprio(0);
    }
    st = (st == 2) ? 0 : st + 1;
    st2 = (st2 == 2) ? 0 : st2 + 1;
  }
  __syncthreads();
  // epilogue: bf16 C tile; Q gets pre-scaled by SCL (softmax scale folding)
  const float oscale = (which == 0) ? SCL : 1.0f;
  ush* Ct = sm;
#pragma unroll
  for (int mi = 0; mi < 8; ++mi)
#pragma unroll
    for (int ni = 0; ni < 2; ++ni)
#pragma unroll
      for (int j = 0; j < 4; ++j)
        Ct[(wm * 128 + mi * 16 + lg * 4 + j) * 128 + wn * 32 + ni * 16 + lr] =
            f2bf(acc[mi][ni][j] * oscale);
  __syncthreads();
  const int m0 = mt * 256, b = m0 >> 11, t0 = m0 & 2047, h0 = n0 >> 6;
  if (which == 2) {
    const int cc = tid & 127, rq = tid >> 7;
    const int hsel = cc >> 6, d = cc & 63;
    ush* dst = Vtg + (size_t)(b * 16 + h0 + hsel) * 131072 + (size_t)d * 2048 +
               t0 + rq * 64;
#pragma unroll
    for (int ch = 0; ch < 8; ++ch) {
      ushx8 v;
#pragma unroll
      for (int k = 0; k < 8; ++k) v[k] = Ct[(rq * 64 + ch * 8 + k) * 128 + cc];
      *(ushx8*)(dst + ch * 8) = v;
    }
  } else {
    ush* Om = QKV + (size_t)which * 8388608;
#pragma unroll
    for (int it = 0; it < 8; ++it) {
      int c = it * 512 + tid;
      int hsel = c >> 11;
      int cc = c & 2047;
      int r = cc >> 3;
      int c8 = (cc & 7) * 8;
      ushx8 v = *(const ushx8*)(Ct + r * 128 + hsel * 64 + c8);
      *(ushx8*)(Om + ((size_t)(b * 16 + h0 + hsel) * 2048 + t0 + r) * 64 + c8) = v;
    }
  }
}

// ---- causal flash attention: r17 staging structure + SWAPPED QK^T.
// mfma(kf, qf) puts S^T in-lane: kv = f*16+lg*4+j, q = lr. P row (q=lr) is
// written with 4 ds_write_b64 (kv-contiguous packs) into the same swizzled
// [q][kv] layout the b128 pf read expects. Private scalar row-sum.
__global__ __launch_bounds__(256) void k_attn(
    const ush* __restrict__ Q, const ush* __restrict__ K,
    const ush* __restrict__ Vg, ush* __restrict__ O) {
  __shared__ __align__(16) ush Ks[2][4096];   // swz [64 kv][64 d], key=kv&7
  __shared__ __align__(16) ush Vs[2][4096];   // swz [64 d][64 kv], key=((d&7)+(d>>3))&7
  __shared__ __align__(16) ush Pl[8][1024];   // per wave x {A,B}: swz [16 q][64 kv], key=q&7
  const int lid = blockIdx.x + 16 * blockIdx.y;
  const int qta = (lid >> 3) & 15;
  const int bh  = ((lid >> 7) << 3) | (lid & 7);
  const int qtb = 31 - qta;
  const size_t hb = (size_t)bh * (2048 * 64);
  const ush* Qh = Q + hb;
  const ush* Kh = K + hb;
  const ush* Vh = Vg + hb;                    // [64 d][2048 t]
  const int tid = threadIdx.x, w = tid >> 6, l = tid & 63, lr = l & 15, lg = l >> 4;
  const int q0a = qta * 64 + w * 16, q0b = qtb * 64 + w * 16;

  short8 qfa[2], qfb[2];
#pragma unroll
  for (int s = 0; s < 2; ++s) {
    qfa[s] = *(const short8*)(Qh + (size_t)(q0a + lr) * 64 + s * 32 + lg * 8);
    qfb[s] = *(const short8*)(Qh + (size_t)(q0b + lr) * 64 + s * 32 + lg * 8);
  }
  f32x4 acca[4] = {}, accb[4] = {};
  float la = 0.f, lb = 0.f;                   // private row sum for q = lr

  int koff[2], voff[2];
#pragma unroll
  for (int it = 0; it < 2; ++it) {
    int ch = it * 256 + tid;
    int r = ch >> 3, g = ch & 7;
    koff[it] = r * 64 + ((g ^ (r & 7)) << 3);
    int keyv = ((r & 7) + (r >> 3)) & 7;
    voff[it] = r * 2048 + ((g ^ keyv) << 3);
  }
  auto issueStage = [&](int c, int buf) {
#pragma unroll
    for (int it = 0; it < 2; ++it) {
      int ch = it * 256 + tid;
      gl_lds16(Kh + (size_t)c * 4096 + koff[it], &Ks[buf][ch * 8]);
      gl_lds16(Vh + c * 64 + voff[it], &Vs[buf][ch * 8]);
    }
  };

  auto ctile = [&](const ush* Kc, const ush* Vc, const short8* qf,
                   f32x4* acc, float& lsum, bool diag, ush* PlW) {
    f32x4 sf[4] = {};
    __builtin_amdgcn_s_setprio(1);
#pragma unroll
    for (int s = 0; s < 2; ++s)
#pragma unroll
      for (int f = 0; f < 4; ++f) {
        int kv = f * 16 + lr;
        short8 kf = *(const short8*)(Kc + kv * 64 + (((s * 4 + lg) ^ (kv & 7)) << 3));
        sf[f] = __builtin_amdgcn_mfma_f32_16x16x32_bf16(kf, qf[s], sf[f], 0, 0, 0);
      }
    __builtin_amdgcn_s_setprio(0);
    // lane holds S^T[kv = f*16 + lg*4 + j][q = lr]  (Q pre-scaled by SCL)
#pragma unroll
    for (int f = 0; f < 4; ++f)
#pragma unroll
      for (int j = 0; j < 4; ++j) {
        float vv = sf[f][j];
        if (diag && (f * 16 + lg * 4 + j) > (w * 16 + lr)) vv = NEG_BIG;
        sf[f][j] = __builtin_amdgcn_exp2f(vv);
      }
#pragma unroll
    for (int f = 0; f < 4; ++f)
      lsum += (sf[f][0] + sf[f][1]) + (sf[f][2] + sf[f][3]);
    // P -> LDS: per f one b64 of 4 kv-contiguous truncated bf16
#pragma unroll
    for (int f = 0; f < 4; ++f) {
      u32 lo = (fbits(sf[f][1]) & 0xffff0000u) | (fbits(sf[f][0]) >> 16);
      u32 hi = (fbits(sf[f][3]) & 0xffff0000u) | (fbits(sf[f][2]) >> 16);
      int chunk = f * 2 + (lg >> 1);
      u32x2 pk; pk[0] = lo; pk[1] = hi;
      *(u32x2*)(PlW + lr * 64 + ((chunk ^ (lr & 7)) << 3) + (lg & 1) * 4) = pk;
    }
    __builtin_amdgcn_s_setprio(1);
#pragma unroll
    for (int s = 0; s < 2; ++s) {
      short8 pf = *(const short8*)(PlW + lr * 64 + (((s * 4 + lg) ^ (lr & 7)) << 3));
#pragma unroll
      for (int db = 0; db < 4; ++db) {
        int dv = db * 16 + lr;
        int keyv = ((dv & 7) + (dv >> 3)) & 7;
        short8 vf = *(const short8*)(Vc + dv * 64 + (((s * 4 + lg) ^ keyv) << 3));
        acc[db] = __builtin_amdgcn_mfma_f32_16x16x32_bf16(pf, vf, acc[db], 0, 0, 0);
      }
    }
    __builtin_amdgcn_s_setprio(0);
  };

  issueStage(0, 0);
  int cur = 0;
  for (int c = 0; c <= qtb; ++c) {
    asm volatile("s_waitcnt vmcnt(0)" ::: "memory");
    __syncthreads();                  // buf[cur] staged; also fences prev compute
    if (c < qtb) issueStage(c + 1, cur ^ 1);
    const ush* Kc = Ks[cur];
    const ush* Vc = Vs[cur];
    if (c <= qta) ctile(Kc, Vc, qfa, acca, la, c == qta, Pl[w]);
    ctile(Kc, Vc, qfb, accb, lb, c == qtb, Pl[4 + w]);
    cur ^= 1;
  }

  // reduce row sums over the 4 lg-lanes (q = lr), broadcast to acc layout
  la += __shfl_xor(la, 16); la += __shfl_xor(la, 32);
  lb += __shfl_xor(lb, 16); lb += __shfl_xor(lb, 32);
  float ra = __builtin_amdgcn_rcpf(la);
  float rb = __builtin_amdgcn_rcpf(lb);
  float ia[4], ib[4];
#pragma unroll
  for (int j = 0; j < 4; ++j) {
    ia[j] = __shfl(ra, lg * 4 + j);
    ib[j] = __shfl(rb, lg * 4 + j);
  }
  ush* Oh = O + hb;
#pragma unroll
  for (int db = 0; db < 4; ++db)
#pragma unroll
    for (int j = 0; j < 4; ++j) {
      Oh[(size_t)(q0a + lg * 4 + j) * 64 + db * 16 + lr] = f2bf(acca[db][j] * ia[j]);
      Oh[(size_t)(q0b + lg * 4 + j) * 64 + db * 16 + lr] = f2bf(accb[db][j] * ib[j]);
    }
}

// ---- permute, LDS-tiled: block (jh,tau,b) -> M[b][128*tau..+128][jh*128..+128]
__global__ __launch_bounds__(256) void k_gather(const ush* __restrict__ Ob, ush* __restrict__ Mb) {
  __shared__ ush Ls[2][128][68];
  const int jh = blockIdx.x, tau = blockIdx.y, b = blockIdx.z;
  const int tid = threadIdx.x;
#pragma unroll
  for (int it = 0; it < 8; ++it) {
    int c = it * 256 + tid;
    int r = c >> 3, d8 = (c & 7) * 8;
    int esel = r >> 7, jlow = r & 127;
    ushx8 v = *(const ushx8*)(Ob +
        ((size_t)(b * 16 + jh + esel * 8) * 2048 + jlow * 16 + tau) * 64 + d8);
    *(ushx8*)(&Ls[esel][jlow][d8]) = v;
  }
  __syncthreads();
  const int wv = tid >> 6, l = tid & 63;
  const int e = wv >> 1, jhalf = wv & 1, d = l;
  ush* Mrow = Mb + (size_t)b * 2097152 +
              (size_t)(128 * tau + 2 * d + e) * 1024 + jh * 128 + jhalf * 64;
#pragma unroll
  for (int ch = 0; ch < 8; ++ch) {
    ushx8 v;
#pragma unroll
    for (int k = 0; k < 8; ++k) v[k] = Ls[e][jhalf * 64 + ch * 8 + k][d];
    *(ushx8*)(Mrow + ch * 8) = v;
  }
}

// ---- output GEMM, 256x128 BK=32 triple-buffer pipeline, f32 epilogue
__global__ __launch_bounds__(512, 2) void k_gemm_out(
    const ush* __restrict__ A, const ush* __restrict__ Bt, float* __restrict__ Out) {
  __shared__ __align__(16) ush sm[36864];
  const int tid = threadIdx.x;
  const int w = tid >> 6, l = tid & 63, lr = l & 15, lg = l >> 4;
  const int wm = w >> 2, wn = w & 3;
  const int mt = blockIdx.x, nt = blockIdx.y;
  const int n0 = nt * 128;
  const ush* Ag = A + (size_t)mt * 256 * 1024;
  const ush* Bg = Bt + (size_t)n0 * 1024;
  int aoff[2], boff;
  {
#pragma unroll
    for (int it = 0; it < 2; ++it) {
      int ch = it * 512 + tid, row = ch >> 2, g = ch & 3;
      aoff[it] = row * 1024 + ((g ^ kkey(row)) << 3);
    }
    int row = tid >> 2, g = tid & 3;
    boff = row * 1024 + ((g ^ kkey(row)) << 3);
  }
  f32x4 acc[8][2] = {};

  auto issueS = [&](int kt, int st) {
    const ush* Asrc = Ag + kt * 32;
    const ush* Bsrc = Bg + kt * 32;
    ush* base = sm + st * 12288;
#pragma unroll
    for (int it = 0; it < 2; ++it)
      gl_lds16(Asrc + aoff[it], base + ((size_t)it * 512 + tid) * 8);
    gl_lds16(Bsrc + boff, base + 8192 + (size_t)tid * 8);
  };

  issueS(0, 0);
  issueS(1, 1);
  int st = 0, st2 = 2;
  for (int t = 0; t < 32; ++t) {
    if (t < 31) {
      asm volatile("s_waitcnt vmcnt(3)" ::: "memory");
    } else {
      asm volatile("s_waitcnt vmcnt(0)" ::: "memory");
    }
    __syncthreads();
    if (t + 2 < 32) issueS(t + 2, st2);
    const ush* Ab = sm + st * 12288;
    const ush* Bb = sm + st * 12288 + 8192;
    short8 fb[2];
#pragma unroll
    for (int ni = 0; ni < 2; ++ni) {
      int row = wn * 32 + ni * 16 + lr;
      fb[ni] = *(const short8*)(Bb + row * 32 + ((lg ^ kkey(row)) << 3));
    }
#pragma unroll
    for (int qm = 0; qm < 4; ++qm) {
      short8 fa[2];
#pragma unroll
      for (int m2 = 0; m2 < 2; ++m2) {
        int row = wm * 128 + (qm * 2 + m2) * 16 + lr;
        fa[m2] = *(const short8*)(Ab + row * 32 + ((lg ^ kkey(row)) << 3));
      }
      __builtin_amdgcn_s_setprio(1);
#pragma unroll
      for (int m2 = 0; m2 < 2; ++m2)
#pragma unroll
        for (int ni = 0; ni < 2; ++ni)
          acc[qm * 2 + m2][ni] = __builtin_amdgcn_mfma_f32_16x16x32_bf16(
              fa[m2], fb[ni], acc[qm * 2 + m2][ni], 0, 0, 0);
      __builtin_amdgcn_s_setprio(0);
    }
    st = (st == 2) ? 0 : st + 1;
    st2 = (st2 == 2) ? 0 : st2 + 1;
  }
  const int m0 = mt * 256;
#pragma unroll
  for (int mi = 0; mi < 8; ++mi)
#pragma unroll
    for (int ni = 0; ni < 2; ++ni)
#pragma unroll
      for (int j = 0; j < 4; ++j)
        Out[(size_t)(m0 + wm * 128 + mi * 16 + lg * 4 + j) * 1024 +
            n0 + wn * 32 + ni * 16 + lr] = acc[mi][ni][j];
}

extern "C" void kernel_launch(void* const* d_in, const int* in_sizes, int n_in,
                              void* d_out, int out_size, void* d_ws, size_t ws_size,
                              hipStream_t stream) {
  const float* x  = (const float*)d_in[0];
  const float* wq = (const float*)d_in[1];
  const float* wk = (const float*)d_in[2];
  const float* wv = (const float*)d_in[3];
  const float* wp = (const float*)d_in[4];
  float* out = (float*)d_out;   // reference output dtype is float32
  char* ws = (char*)d_ws;
  ush* xb  = (ush*)ws;                 // [0,16MB): x bf16; dead after qkv GEMM
  ush* wt  = (ush*)(ws + 16777216);    // [16,24MB): Wq^T,Wk^T,Wv^T,Wp^T bf16
  ush* qkv = (ush*)(ws + 25165824);    // [24,72MB): Q(pre-scaled),K
  ush* vtg = (ush*)(ws + 75497472);    // [72,88MB): V^T [bh][64][2048]
  ush* ob  = qkv;                      // attn out aliases Q (own-rows r->w)
  ush* mb  = xb;                       // permuted M reuses xb after attn

  k_prep<<<dim3(5120), 256, 0, stream>>>(x, wq, wk, wv, wp, xb, wt);
  k_gemm_qkv<<<dim3(32, 24), 512, 0, stream>>>(xb, wt, qkv, vtg);
  k_attn<<<dim3(16, 64), 256, 0, stream>>>(qkv, qkv + 8388608, vtg, ob);
  k_gather<<<dim3(8, 16, 4), 256, 0, stream>>>(ob, mb);
  k_gemm_out<<<dim3(32, 8), 512, 0, stream>>>(mb, wt + 3145728, out);
}

// Round 19
// 183.296 us; speedup vs baseline: 1.3215x; 1.0350x over previous
//
#include <hip/hip_runtime.h>

typedef unsigned short ush;
typedef unsigned int u32;
typedef __attribute__((ext_vector_type(4))) float f32x4;
typedef __attribute__((ext_vector_type(2))) u32 u32x2;
typedef __attribute__((ext_vector_type(8))) short short8;
typedef __attribute__((ext_vector_type(8))) ush ushx8;
typedef __attribute__((ext_vector_type(4))) ush ushx4;

#define GAS __attribute__((address_space(1)))
#define LAS __attribute__((address_space(3)))

__device__ __forceinline__ void gl_lds16(const void* g, void* l) {
  __builtin_amdgcn_global_load_lds((const GAS void*)g, (LAS void*)l, 16, 0, 0);
}

// manual RNE f32->bf16 (proven)
__device__ __forceinline__ ush f2bf(float f) {
  union { float f; unsigned int u; } x; x.f = f;
  unsigned int r = x.u + 0x7fffu + ((x.u >> 16) & 1u);
  return (ush)(r >> 16);
}
__device__ __forceinline__ u32 fbits(float f) {
  union { float f; u32 u; } x; x.f = f; return x.u;
}

#define NEG_BIG (-1.0e4f)
// 1/sqrt(64) * log2(e): folded into Q during the QKV GEMM epilogue
#define SCL 0.18033688f

// BK=32 row swizzle: 4 chunks (16B) per row
__device__ __forceinline__ int kkey(int row) { return ((row & 3) + (row >> 2)) & 3; }

// ---- merged prep: blocks [0,4096) convert x f32->bf16; [4096,5120) transpose W
__global__ __launch_bounds__(256) void k_prep(
    const float* __restrict__ X, const float* __restrict__ W0,
    const float* __restrict__ W1, const float* __restrict__ W2,
    const float* __restrict__ W3, ush* __restrict__ Xb, ush* __restrict__ Wt) {
  __shared__ ush Ts[64][72];
  const int bx = blockIdx.x;
  if (bx < 4096) {
    int idx = bx * 256 + threadIdx.x;
    int base = idx * 8;
    f32x4 a = *(const f32x4*)(X + base);
    f32x4 b = *(const f32x4*)(X + base + 4);
    ushx8 o;
#pragma unroll
    for (int q = 0; q < 4; ++q) { o[q] = f2bf(a[q]); o[4 + q] = f2bf(b[q]); }
    *(ushx8*)(Xb + base) = o;
    return;
  }
  const int bid = bx - 4096;
  const int z = bid >> 8;
  const int k0 = (bid & 15) * 64, n0 = ((bid >> 4) & 15) * 64;
  const float* W = (z == 0) ? W0 : (z == 1) ? W1 : (z == 2) ? W2 : W3;
  ush* Ot = Wt + (size_t)z * 1048576;
  const int rr = threadIdx.x >> 4, cc = threadIdx.x & 15;
#pragma unroll
  for (int i = 0; i < 4; ++i) {
    int row = i * 16 + rr;
    f32x4 v = *(const f32x4*)(W + (size_t)(k0 + row) * 1024 + n0 + cc * 4);
#pragma unroll
    for (int q = 0; q < 4; ++q) Ts[row][cc * 4 + q] = f2bf(v[q]);
  }
  __syncthreads();
#pragma unroll
  for (int i = 0; i < 4; ++i) {
    int n = i * 16 + rr;
    ushx4 o;
#pragma unroll
    for (int q = 0; q < 4; ++q) o[q] = Ts[cc * 4 + q][n];
    *(ushx4*)(Ot + (size_t)(n0 + n) * 1024 + k0 + cc * 4) = o;
  }
}

// ---- fused QKV GEMM, 256x128 tile, BK=32, triple-buffered, counted vmcnt.
// Q output (which==0) pre-scaled by SCL. V blocks (which==2) write V^T.
__global__ __launch_bounds__(512, 2) void k_gemm_qkv(
    const ush* __restrict__ X, const ush* __restrict__ Wt,
    ush* __restrict__ QKV, ush* __restrict__ Vtg) {
  __shared__ __align__(16) ush sm[36864];   // 3 stages x (A 8192 + B 4096)
  const int tid = threadIdx.x;
  const int w = tid >> 6, l = tid & 63, lr = l & 15, lg = l >> 4;
  const int wm = w >> 2, wn = w & 3;
  const int mt = blockIdx.x, nt = blockIdx.y;
  const int which = nt >> 3, n0 = (nt & 7) * 128;
  const ush* Ag = X + (size_t)mt * 256 * 1024;
  const ush* Bg = Wt + (size_t)which * 1048576 + (size_t)n0 * 1024;
  int aoff[2], boff;
  {
#pragma unroll
    for (int it = 0; it < 2; ++it) {
      int ch = it * 512 + tid, row = ch >> 2, g = ch & 3;
      aoff[it] = row * 1024 + ((g ^ kkey(row)) << 3);
    }
    int row = tid >> 2, g = tid & 3;
    boff = row * 1024 + ((g ^ kkey(row)) << 3);
  }
  f32x4 acc[8][2] = {};

  auto issueS = [&](int kt, int st) {
    const ush* Asrc = Ag + kt * 32;
    const ush* Bsrc = Bg + kt * 32;
    ush* base = sm + st * 12288;
#pragma unroll
    for (int it = 0; it < 2; ++it)
      gl_lds16(Asrc + aoff[it], base + ((size_t)it * 512 + tid) * 8);
    gl_lds16(Bsrc + boff, base + 8192 + (size_t)tid * 8);
  };

  issueS(0, 0);
  issueS(1, 1);
  int st = 0, st2 = 2;
  for (int t = 0; t < 32; ++t) {
    if (t < 31) {
      asm volatile("s_waitcnt vmcnt(3)" ::: "memory");
    } else {
      asm volatile("s_waitcnt vmcnt(0)" ::: "memory");
    }
    __syncthreads();
    if (t + 2 < 32) issueS(t + 2, st2);
    const ush* Ab = sm + st * 12288;
    const ush* Bb = sm + st * 12288 + 8192;
    short8 fb[2];
#pragma unroll
    for (int ni = 0; ni < 2; ++ni) {
      int row = wn * 32 + ni * 16 + lr;
      fb[ni] = *(const short8*)(Bb + row * 32 + ((lg ^ kkey(row)) << 3));
    }
#pragma unroll
    for (int qm = 0; qm < 4; ++qm) {
      short8 fa[2];
#pragma unroll
      for (int m2 = 0; m2 < 2; ++m2) {
        int row = wm * 128 + (qm * 2 + m2) * 16 + lr;
        fa[m2] = *(const short8*)(Ab + row * 32 + ((lg ^ kkey(row)) << 3));
      }
      __builtin_amdgcn_s_setprio(1);
#pragma unroll
      for (int m2 = 0; m2 < 2; ++m2)
#pragma unroll
        for (int ni = 0; ni < 2; ++ni)
          acc[qm * 2 + m2][ni] = __builtin_amdgcn_mfma_f32_16x16x32_bf16(
              fa[m2], fb[ni], acc[qm * 2 + m2][ni], 0, 0, 0);
      __builtin_amdgcn_s_setprio(0);
    }
    st = (st == 2) ? 0 : st + 1;
    st2 = (st2 == 2) ? 0 : st2 + 1;
  }
  __syncthreads();
  // epilogue: bf16 C tile; Q gets pre-scaled by SCL (softmax scale folding)
  const float oscale = (which == 0) ? SCL : 1.0f;
  ush* Ct = sm;
#pragma unroll
  for (int mi = 0; mi < 8; ++mi)
#pragma unroll
    for (int ni = 0; ni < 2; ++ni)
#pragma unroll
      for (int j = 0; j < 4; ++j)
        Ct[(wm * 128 + mi * 16 + lg * 4 + j) * 128 + wn * 32 + ni * 16 + lr] =
            f2bf(acc[mi][ni][j] * oscale);
  __syncthreads();
  const int m0 = mt * 256, b = m0 >> 11, t0 = m0 & 2047, h0 = n0 >> 6;
  if (which == 2) {
    const int cc = tid & 127, rq = tid >> 7;
    const int hsel = cc >> 6, d = cc & 63;
    ush* dst = Vtg + (size_t)(b * 16 + h0 + hsel) * 131072 + (size_t)d * 2048 +
               t0 + rq * 64;
#pragma unroll
    for (int ch = 0; ch < 8; ++ch) {
      ushx8 v;
#pragma unroll
      for (int k = 0; k < 8; ++k) v[k] = Ct[(rq * 64 + ch * 8 + k) * 128 + cc];
      *(ushx8*)(dst + ch * 8) = v;
    }
  } else {
    ush* Om = QKV + (size_t)which * 8388608;
#pragma unroll
    for (int it = 0; it < 8; ++it) {
      int c = it * 512 + tid;
      int hsel = c >> 11;
      int cc = c & 2047;
      int r = cc >> 3;
      int c8 = (cc & 7) * 8;
      ushx8 v = *(const ushx8*)(Ct + r * 128 + hsel * 64 + c8);
      *(ushx8*)(Om + ((size_t)(b * 16 + h0 + hsel) * 2048 + t0 + r) * 64 + c8) = v;
    }
  }
}

// ---- causal flash attention, QBLK=128: block owns q-tiles qta (128 rows)
// and qtb=15-qta; each wave owns 32 q rows (2 x 16-row subtiles). kf/vf are
// hoisted to registers once per kv-step and shared by all 4 subtile-ctiles.
// Swapped QK^T (S^T in-lane), 4 private Pl buffers per wave.
__global__ __launch_bounds__(256, 2) void k_attn(
    const ush* __restrict__ Q, const ush* __restrict__ K,
    const ush* __restrict__ Vg, ush* __restrict__ O) {
  __shared__ __align__(16) ush Ks[2][4096];   // swz [64 kv][64 d], key=kv&7
  __shared__ __align__(16) ush Vs[2][4096];   // swz [64 d][64 kv], key=((d&7)+(d>>3))&7
  __shared__ __align__(16) ush Pl[16][1024];  // wave x {A0,A1,B0,B1}
  const int lid = blockIdx.x + 8 * blockIdx.y;  // 512 blocks
  const int qta = (lid >> 3) & 7;
  const int bh  = ((lid >> 6) << 3) | (lid & 7);
  const int qtb = 15 - qta;
  const size_t hb = (size_t)bh * (2048 * 64);
  const ush* Qh = Q + hb;
  const ush* Kh = K + hb;
  const ush* Vh = Vg + hb;                    // [64 d][2048 t]
  const int tid = threadIdx.x, w = tid >> 6, l = tid & 63, lr = l & 15, lg = l >> 4;
  const int qbA = qta * 128 + w * 32, qbB = qtb * 128 + w * 32;

  short8 qfA[2][2], qfB[2][2];                // [sub][s]
#pragma unroll
  for (int sub = 0; sub < 2; ++sub)
#pragma unroll
    for (int s = 0; s < 2; ++s) {
      qfA[sub][s] = *(const short8*)(Qh + (size_t)(qbA + sub * 16 + lr) * 64 + s * 32 + lg * 8);
      qfB[sub][s] = *(const short8*)(Qh + (size_t)(qbB + sub * 16 + lr) * 64 + s * 32 + lg * 8);
    }
  f32x4 accA[2][4] = {}, accB[2][4] = {};
  float lA[2] = {0.f, 0.f}, lB[2] = {0.f, 0.f};

  const int dA0 = 2 * qta + ((2 * w + 0) >> 2), dA1 = 2 * qta + ((2 * w + 1) >> 2);
  const int dB0 = 2 * qtb + ((2 * w + 0) >> 2), dB1 = 2 * qtb + ((2 * w + 1) >> 2);
  const int qo0 = ((2 * w + 0) & 3) * 16, qo1 = ((2 * w + 1) & 3) * 16;

  int koff[2], voff[2];
#pragma unroll
  for (int it = 0; it < 2; ++it) {
    int ch = it * 256 + tid;
    int r = ch >> 3, g = ch & 7;
    koff[it] = r * 64 + ((g ^ (r & 7)) << 3);
    int keyv = ((r & 7) + (r >> 3)) & 7;
    voff[it] = r * 2048 + ((g ^ keyv) << 3);
  }
  auto issueStage = [&](int c, int buf) {
#pragma unroll
    for (int it = 0; it < 2; ++it) {
      int ch = it * 256 + tid;
      gl_lds16(Kh + (size_t)c * 4096 + koff[it], &Ks[buf][ch * 8]);
      gl_lds16(Vh + c * 64 + voff[it], &Vs[buf][ch * 8]);
    }
  };

  short8 kf[2][4], vf[2][4];
  // one 16-row q-subtile against hoisted kf/vf
  auto csub = [&](const short8* qf, f32x4* acc, float& lsum, bool diag,
                  int qoff, ush* PlW) {
    f32x4 sf[4] = {};
    __builtin_amdgcn_s_setprio(1);
#pragma unroll
    for (int s = 0; s < 2; ++s)
#pragma unroll
      for (int f = 0; f < 4; ++f)
        sf[f] = __builtin_amdgcn_mfma_f32_16x16x32_bf16(kf[s][f], qf[s], sf[f], 0, 0, 0);
    __builtin_amdgcn_s_setprio(0);
    // lane holds S^T[kv = f*16 + lg*4 + j][q = lr]
#pragma unroll
    for (int f = 0; f < 4; ++f)
#pragma unroll
      for (int j = 0; j < 4; ++j) {
        float vv = sf[f][j];
        if (diag && (f * 16 + lg * 4 + j) > (qoff + lr)) vv = NEG_BIG;
        sf[f][j] = __builtin_amdgcn_exp2f(vv);
      }
#pragma unroll
    for (int f = 0; f < 4; ++f)
      lsum += (sf[f][0] + sf[f][1]) + (sf[f][2] + sf[f][3]);
#pragma unroll
    for (int f = 0; f < 4; ++f) {
      u32 lo = (fbits(sf[f][1]) & 0xffff0000u) | (fbits(sf[f][0]) >> 16);
      u32 hi = (fbits(sf[f][3]) & 0xffff0000u) | (fbits(sf[f][2]) >> 16);
      int chunk = f * 2 + (lg >> 1);
      u32x2 pk; pk[0] = lo; pk[1] = hi;
      *(u32x2*)(PlW + lr * 64 + ((chunk ^ (lr & 7)) << 3) + (lg & 1) * 4) = pk;
    }
    __builtin_amdgcn_s_setprio(1);
#pragma unroll
    for (int s = 0; s < 2; ++s) {
      short8 pf = *(const short8*)(PlW + lr * 64 + (((s * 4 + lg) ^ (lr & 7)) << 3));
#pragma unroll
      for (int db = 0; db < 4; ++db)
        acc[db] = __builtin_amdgcn_mfma_f32_16x16x32_bf16(pf, vf[s][db], acc[db], 0, 0, 0);
    }
    __builtin_amdgcn_s_setprio(0);
  };

  issueStage(0, 0);
  int cur = 0;
  const int cmax = 2 * qtb + 2;
  for (int c = 0; c < cmax; ++c) {
    asm volatile("s_waitcnt vmcnt(0)" ::: "memory");
    __syncthreads();                  // buf[cur] staged; fences prev compute
    if (c + 1 < cmax) issueStage(c + 1, cur ^ 1);
    const ush* Kc = Ks[cur];
    const ush* Vc = Vs[cur];
    // hoist kf/vf once per step (shared by all 4 subtiles)
#pragma unroll
    for (int s = 0; s < 2; ++s)
#pragma unroll
      for (int f = 0; f < 4; ++f)
        kf[s][f] = *(const short8*)(Kc + (f * 16 + lr) * 64 + (((s * 4 + lg) ^ (lr & 7)) << 3));
#pragma unroll
    for (int s = 0; s < 2; ++s)
#pragma unroll
      for (int db = 0; db < 4; ++db) {
        int dv = db * 16 + lr;
        int keyv = ((dv & 7) + (dv >> 3)) & 7;
        vf[s][db] = *(const short8*)(Vc + dv * 64 + (((s * 4 + lg) ^ keyv) << 3));
      }
    if (c <= dA0) csub(qfA[0], accA[0], lA[0], c == dA0, qo0, Pl[(w << 2) | 0]);
    if (c <= dA1) csub(qfA[1], accA[1], lA[1], c == dA1, qo1, Pl[(w << 2) | 1]);
    if (c <= dB0) csub(qfB[0], accB[0], lB[0], c == dB0, qo0, Pl[(w << 2) | 2]);
    if (c <= dB1) csub(qfB[1], accB[1], lB[1], c == dB1, qo1, Pl[(w << 2) | 3]);
    cur ^= 1;
  }

  // reduce row sums over the 4 lg-lanes (q = lr), broadcast to acc layout
  ush* Oh = O + hb;
#pragma unroll
  for (int sub = 0; sub < 2; ++sub) {
    float la = lA[sub], lb = lB[sub];
    la += __shfl_xor(la, 16); la += __shfl_xor(la, 32);
    lb += __shfl_xor(lb, 16); lb += __shfl_xor(lb, 32);
    float ra = __builtin_amdgcn_rcpf(la);
    float rb = __builtin_amdgcn_rcpf(lb);
#pragma unroll
    for (int j = 0; j < 4; ++j) {
      float ia = __shfl(ra, lg * 4 + j);
      float ib = __shfl(rb, lg * 4 + j);
#pragma unroll
      for (int db = 0; db < 4; ++db) {
        Oh[(size_t)(qbA + sub * 16 + lg * 4 + j) * 64 + db * 16 + lr] =
            f2bf(accA[sub][db][j] * ia);
        Oh[(size_t)(qbB + sub * 16 + lg * 4 + j) * 64 + db * 16 + lr] =
            f2bf(accB[sub][db][j] * ib);
      }
    }
  }
}

// ---- permute, LDS-tiled: block (jh,tau,b) -> M[b][128*tau..+128][jh*128..+128]
__global__ __launch_bounds__(256) void k_gather(const ush* __restrict__ Ob, ush* __restrict__ Mb) {
  __shared__ ush Ls[2][128][68];
  const int jh = blockIdx.x, tau = blockIdx.y, b = blockIdx.z;
  const int tid = threadIdx.x;
#pragma unroll
  for (int it = 0; it < 8; ++it) {
    int c = it * 256 + tid;
    int r = c >> 3, d8 = (c & 7) * 8;
    int esel = r >> 7, jlow = r & 127;
    ushx8 v = *(const ushx8*)(Ob +
        ((size_t)(b * 16 + jh + esel * 8) * 2048 + jlow * 16 + tau) * 64 + d8);
    *(ushx8*)(&Ls[esel][jlow][d8]) = v;
  }
  __syncthreads();
  const int wv = tid >> 6, l = tid & 63;
  const int e = wv >> 1, jhalf = wv & 1, d = l;
  ush* Mrow = Mb + (size_t)b * 2097152 +
              (size_t)(128 * tau + 2 * d + e) * 1024 + jh * 128 + jhalf * 64;
#pragma unroll
  for (int ch = 0; ch < 8; ++ch) {
    ushx8 v;
#pragma unroll
    for (int k = 0; k < 8; ++k) v[k] = Ls[e][jhalf * 64 + ch * 8 + k][d];
    *(ushx8*)(Mrow + ch * 8) = v;
  }
}

// ---- output GEMM, 256x128 BK=32 triple-buffer pipeline, f32 epilogue
__global__ __launch_bounds__(512, 2) void k_gemm_out(
    const ush* __restrict__ A, const ush* __restrict__ Bt, float* __restrict__ Out) {
  __shared__ __align__(16) ush sm[36864];
  const int tid = threadIdx.x;
  const int w = tid >> 6, l = tid & 63, lr = l & 15, lg = l >> 4;
  const int wm = w >> 2, wn = w & 3;
  const int mt = blockIdx.x, nt = blockIdx.y;
  const int n0 = nt * 128;
  const ush* Ag = A + (size_t)mt * 256 * 1024;
  const ush* Bg = Bt + (size_t)n0 * 1024;
  int aoff[2], boff;
  {
#pragma unroll
    for (int it = 0; it < 2; ++it) {
      int ch = it * 512 + tid, row = ch >> 2, g = ch & 3;
      aoff[it] = row * 1024 + ((g ^ kkey(row)) << 3);
    }
    int row = tid >> 2, g = tid & 3;
    boff = row * 1024 + ((g ^ kkey(row)) << 3);
  }
  f32x4 acc[8][2] = {};

  auto issueS = [&](int kt, int st) {
    const ush* Asrc = Ag + kt * 32;
    const ush* Bsrc = Bg + kt * 32;
    ush* base = sm + st * 12288;
#pragma unroll
    for (int it = 0; it < 2; ++it)
      gl_lds16(Asrc + aoff[it], base + ((size_t)it * 512 + tid) * 8);
    gl_lds16(Bsrc + boff, base + 8192 + (size_t)tid * 8);
  };

  issueS(0, 0);
  issueS(1, 1);
  int st = 0, st2 = 2;
  for (int t = 0; t < 32; ++t) {
    if (t < 31) {
      asm volatile("s_waitcnt vmcnt(3)" ::: "memory");
    } else {
      asm volatile("s_waitcnt vmcnt(0)" ::: "memory");
    }
    __syncthreads();
    if (t + 2 < 32) issueS(t + 2, st2);
    const ush* Ab = sm + st * 12288;
    const ush* Bb = sm + st * 12288 + 8192;
    short8 fb[2];
#pragma unroll
    for (int ni = 0; ni < 2; ++ni) {
      int row = wn * 32 + ni * 16 + lr;
      fb[ni] = *(const short8*)(Bb + row * 32 + ((lg ^ kkey(row)) << 3));
    }
#pragma unroll
    for (int qm = 0; qm < 4; ++qm) {
      short8 fa[2];
#pragma unroll
      for (int m2 = 0; m2 < 2; ++m2) {
        int row = wm * 128 + (qm * 2 + m2) * 16 + lr;
        fa[m2] = *(const short8*)(Ab + row * 32 + ((lg ^ kkey(row)) << 3));
      }
      __builtin_amdgcn_s_setprio(1);
#pragma unroll
      for (int m2 = 0; m2 < 2; ++m2)
#pragma unroll
        for (int ni = 0; ni < 2; ++ni)
          acc[qm * 2 + m2][ni] = __builtin_amdgcn_mfma_f32_16x16x32_bf16(
              fa[m2], fb[ni], acc[qm * 2 + m2][ni], 0, 0, 0);
      __builtin_amdgcn_s_setprio(0);
    }
    st = (st == 2) ? 0 : st + 1;
    st2 = (st2 == 2) ? 0 : st2 + 1;
  }
  const int m0 = mt * 256;
#pragma unroll
  for (int mi = 0; mi < 8; ++mi)
#pragma unroll
    for (int ni = 0; ni < 2; ++ni)
#pragma unroll
      for (int j = 0; j < 4; ++j)
        Out[(size_t)(m0 + wm * 128 + mi * 16 + lg * 4 + j) * 1024 +
            n0 + wn * 32 + ni * 16 + lr] = acc[mi][ni][j];
}

extern "C" void kernel_launch(void* const* d_in, const int* in_sizes, int n_in,
                              void* d_out, int out_size, void* d_ws, size_t ws_size,
                              hipStream_t stream) {
  const float* x  = (const float*)d_in[0];
  const float* wq = (const float*)d_in[1];
  const float* wk = (const float*)d_in[2];
  const float* wv = (const float*)d_in[3];
  const float* wp = (const float*)d_in[4];
  float* out = (float*)d_out;   // reference output dtype is float32
  char* ws = (char*)d_ws;
  ush* xb  = (ush*)ws;                 // [0,16MB): x bf16; dead after qkv GEMM
  ush* wt  = (ush*)(ws + 16777216);    // [16,24MB): Wq^T,Wk^T,Wv^T,Wp^T bf16
  ush* qkv = (ush*)(ws + 25165824);    // [24,72MB): Q(pre-scaled),K
  ush* vtg = (ush*)(ws + 75497472);    // [72,88MB): V^T [bh][64][2048]
  ush* ob  = qkv;                      // attn out aliases Q (own-rows r->w)
  ush* mb  = xb;                       // permuted M reuses xb after attn

  k_prep<<<dim3(5120), 256, 0, stream>>>(x, wq, wk, wv, wp, xb, wt);
  k_gemm_qkv<<<dim3(32, 24), 512, 0, stream>>>(xb, wt, qkv, vtg);
  k_attn<<<dim3(8, 64), 256, 0, stream>>>(qkv, qkv + 8388608, vtg, ob);
  k_gather<<<dim3(8, 16, 4), 256, 0, stream>>>(ob, mb);
  k_gemm_out<<<dim3(32, 8), 512, 0, stream>>>(mb, wt + 3145728, out);
}